// Round 2
// baseline (2008.985 us; speedup 1.0000x reference)
//
#include <hip/hip_runtime.h>
#include <hip/hip_bf16.h>
#include <stdint.h>

using bf16 = __hip_bfloat16;
typedef __bf16 bf16x8v __attribute__((ext_vector_type(8)));
typedef float f32x4 __attribute__((ext_vector_type(4)));

#define MFMA16(a,b,c) __builtin_amdgcn_mfma_f32_16x16x32_bf16((a),(b),(c),0,0,0)

__device__ __forceinline__ float tof(bf16 h){ return __bfloat162float(h); }
__device__ __forceinline__ bf16 tob(float f){ return __float2bfloat16(f); }

__device__ __forceinline__ void gll16(const void* g, void* l) {
    __builtin_amdgcn_global_load_lds((const __attribute__((address_space(1))) void*)g,
                                     (__attribute__((address_space(3))) void*)l, 16, 0, 0);
}

// ---------------- zero-fill (uint4 granularity) ----------------
__global__ __launch_bounds__(256)
void zero_k(uint4* __restrict__ p, size_t n)
{
    size_t i = (size_t)blockIdx.x * 256 + threadIdx.x;
    size_t st = (size_t)gridDim.x * 256;
    uint4 z = make_uint4(0u, 0u, 0u, 0u);
    for (; i < n; i += st) p[i] = z;
}

// ---------------- transpose + cast: out[c][r] = (bf16)in[r][c] ----------------
__global__ __launch_bounds__(256)
void transpose_cast(const float* __restrict__ in, bf16* __restrict__ out, int R, int C)
{
    __shared__ float t[32][33];
    int bx = blockIdx.x * 32, by = blockIdx.y * 32;
    int tx = threadIdx.x & 31, ty = threadIdx.x >> 5;
#pragma unroll
    for (int i = 0; i < 4; ++i)
        t[ty + i*8][tx] = in[(size_t)(by + ty + i*8) * C + bx + tx];
    __syncthreads();
#pragma unroll
    for (int i = 0; i < 4; ++i)
        out[(size_t)(bx + ty + i*8) * R + by + tx] = tob(t[tx][ty + i*8]);
}

// ---------------- LayerNorm over 1024, one block per row ----------------
template<bool OUT32>
__global__ __launch_bounds__(256)
void ln_k(const float* __restrict__ x, const float* __restrict__ g,
          const float* __restrict__ b, void* __restrict__ out)
{
    int row = blockIdx.x, tid = threadIdx.x;
    const float4 v = ((const float4*)(x + (size_t)row*1024))[tid];
    float s = v.x + v.y + v.z + v.w;
    float q = v.x*v.x + v.y*v.y + v.z*v.z + v.w*v.w;
#pragma unroll
    for (int m = 1; m < 64; m <<= 1) { s += __shfl_xor(s, m); q += __shfl_xor(q, m); }
    __shared__ float red[8];
    if ((tid & 63) == 0) { red[tid>>6] = s; red[4 + (tid>>6)] = q; }
    __syncthreads();
    float ts = red[0]+red[1]+red[2]+red[3];
    float tq = red[4]+red[5]+red[6]+red[7];
    float mean = ts * (1.f/1024.f);
    float var  = tq * (1.f/1024.f) - mean*mean;
    float rs = rsqrtf(var + 1e-5f);
    const float4 gv = ((const float4*)g)[tid];
    const float4 bv = ((const float4*)b)[tid];
    float o0 = (v.x-mean)*rs*gv.x + bv.x;
    float o1 = (v.y-mean)*rs*gv.y + bv.y;
    float o2 = (v.z-mean)*rs*gv.z + bv.z;
    float o3 = (v.w-mean)*rs*gv.w + bv.w;
    if (OUT32) {
        ((float4*)out)[(size_t)row*256 + tid] = make_float4(o0,o1,o2,o3);
    } else {
        bf16 tmp[4] = { tob(o0), tob(o1), tob(o2), tob(o3) };
        ((uint2*)out)[(size_t)row*256 + tid] = *(const uint2*)tmp;
    }
}

// ---------------- GEMM: C[M,N] = A[M,K](lda) @ BT[N,K]^T, bf16 in, fp32 acc ----
// EP 0: bias+silu -> bf16 (ld=N)   EP 1: bias -> bf16 (ld=N)
// EP 2: resid + alpha*(acc+bias) -> f32 (ld=N)
// EP 3: qkv scatter (o0=q blocked *SCALE, o1=k blocked, o2=v transposed)
template<int EP>
__global__ __launch_bounds__(256, 2)
void gemm_bt(const bf16* __restrict__ A, const bf16* __restrict__ BT,
             int M, int N, int K, int lda,
             const float* __restrict__ bias, const float* resid, float alpha,
             void* o0, void* o1, void* o2)
{
    (void)M;
    __shared__ bf16 sA[2][4096];
    __shared__ bf16 sB[2][4096];
    const int tid = threadIdx.x;
    const int lane = tid & 63, wid = tid >> 6;
    const int wm = wid >> 1, wn = wid & 1;
    const int bn0 = blockIdx.x * 128, bm0 = blockIdx.y * 128;
    const int fr = lane & 15, fq = lane >> 4;
    const int nk = K >> 5;

    f32x4 acc[4][4];
    const f32x4 vzero = {0.f, 0.f, 0.f, 0.f};
#pragma unroll
    for (int i = 0; i < 4; ++i)
#pragma unroll
        for (int j = 0; j < 4; ++j) acc[i][j] = vzero;

    const bf16* Abase = A + (size_t)bm0 * lda;
    const bf16* Bbase = BT + (size_t)bn0 * K;

    auto stage = [&](int kb, int buf) {
#pragma unroll
        for (int rd = 0; rd < 2; ++rd) {
            int s = rd*256 + tid;
            int r = s >> 2, ko = (s & 3) * 8;
            gll16(Abase + (size_t)r*lda + kb*32 + ko, &sA[buf][s*8]);
            gll16(Bbase + (size_t)r*K   + kb*32 + ko, &sB[buf][s*8]);
        }
    };

    stage(0, 0);
    for (int kb = 0; kb < nk; ++kb) {
        __syncthreads();
        if (kb + 1 < nk) stage(kb+1, (kb+1) & 1);
        const bf16* sa = sA[kb & 1];
        const bf16* sb = sB[kb & 1];
        bf16x8v af[4], bfv[4];
#pragma unroll
        for (int mi = 0; mi < 4; ++mi)
            af[mi] = *(const bf16x8v*)(sa + (wm*64 + mi*16 + fr)*32 + fq*8);
#pragma unroll
        for (int ni = 0; ni < 4; ++ni)
            bfv[ni] = *(const bf16x8v*)(sb + (wn*64 + ni*16 + fr)*32 + fq*8);
#pragma unroll
        for (int mi = 0; mi < 4; ++mi)
#pragma unroll
            for (int ni = 0; ni < 4; ++ni)
                acc[mi][ni] = MFMA16(af[mi], bfv[ni], acc[mi][ni]);
    }

#pragma unroll
    for (int mi = 0; mi < 4; ++mi)
#pragma unroll
    for (int ni = 0; ni < 4; ++ni)
#pragma unroll
    for (int r = 0; r < 4; ++r) {
        int row = bm0 + wm*64 + mi*16 + fq*4 + r;
        int col = bn0 + wn*64 + ni*16 + fr;
        float v = acc[mi][ni][r];
        if (EP == 0) {
            v += bias[col];
            v = v * (1.f / (1.f + __expf(-v)));
            ((bf16*)o0)[(size_t)row * N + col] = tob(v);
        } else if (EP == 1) {
            v += bias[col];
            ((bf16*)o0)[(size_t)row * N + col] = tob(v);
        } else if (EP == 2) {
            float o = resid[(size_t)row * N + col] + alpha * (v + bias[col]);
            ((float*)o0)[(size_t)row * N + col] = o;
        } else {
            int sec = col >> 10, hh = (col >> 7) & 7, d = col & 127;
            int blk = (row / 200) * 8 + hh, c = row % 200;
            if (sec == 0)      ((bf16*)o0)[((size_t)blk*208 + c)*128 + d] = tob(v * 0.08838834764831845f);
            else if (sec == 1) ((bf16*)o1)[((size_t)blk*208 + c)*128 + d] = tob(v);
            else               ((bf16*)o2)[((size_t)blk*128 + d)*224 + c] = tob(v);
        }
    }
}

// ---------------- Shaw positional scores: pos[c][bmh][r] = q[bmh,c,:]·pe[dists[c,r],:]
// grid (10, 200): one wave computes 64 bmh rows x 208 r for a fixed c.
__global__ __launch_bounds__(64)
void pos_kernel(const bf16* __restrict__ qb, const float* __restrict__ pe,
                const int* __restrict__ dists, bf16* __restrict__ pbuf)
{
    const int c = blockIdx.y, mt = blockIdx.x;
    const int lane = threadIdx.x;
    const int fr = lane & 15, fq = lane >> 4;
    bf16x8v qa[4][4];
#pragma unroll
    for (int sub = 0; sub < 4; ++sub)
#pragma unroll
        for (int kk = 0; kk < 4; ++kk)
            qa[sub][kk] = *(const bf16x8v*)(qb + ((size_t)(mt*64 + sub*16 + fr)*208 + c)*128 + kk*32 + fq*8);

    for (int rt = 0; rt < 13; ++rt) {
        int r = rt*16 + fr;
        int pidx = (r < 200) ? dists[c*200 + r] : 0;
        bf16x8v bv[4];
#pragma unroll
        for (int kk = 0; kk < 4; ++kk) {
            const float* pp = pe + (size_t)pidx*128 + kk*32 + fq*8;
            f32x4 lo = *(const f32x4*)pp;
            f32x4 hi = *(const f32x4*)(pp + 4);
            bf16x8v t;
#pragma unroll
            for (int j = 0; j < 4; ++j) { t[j] = (__bf16)lo[j]; t[4+j] = (__bf16)hi[j]; }
            bv[kk] = t;
        }
#pragma unroll
        for (int sub = 0; sub < 4; ++sub) {
            f32x4 a = {0.f,0.f,0.f,0.f};
#pragma unroll
            for (int kk = 0; kk < 4; ++kk) a = MFMA16(qa[sub][kk], bv[kk], a);
            int bmh = mt*64 + sub*16 + fq*4;
#pragma unroll
            for (int g = 0; g < 4; ++g)
                pbuf[((size_t)c*640 + bmh + g)*208 + r] = tob(a[g]);
        }
    }
}

// ---------------- attention core: one block per (b,m,h); 4 waves ----------------
__global__ __launch_bounds__(256, 2)
void attn_core(const bf16* __restrict__ qb, const bf16* __restrict__ kb,
               const bf16* __restrict__ vt, const bf16* __restrict__ pb,
               bf16* __restrict__ ob)
{
    __shared__ bf16 P[4][16][224];
    const int blk = blockIdx.x;
    const int tid = threadIdx.x, lane = tid & 63, w = tid >> 6;
    const int fr = lane & 15, fq = lane >> 4;
    const size_t qkbase = (size_t)blk * 208 * 128;
    const size_t vbase  = (size_t)blk * 128 * 224;

    for (int qc = w; qc < 13; qc += 4) {
        bf16x8v qa[4];
#pragma unroll
        for (int kk = 0; kk < 4; ++kk)
            qa[kk] = *(const bf16x8v*)(qb + qkbase + (size_t)(qc*16 + fr)*128 + kk*32 + fq*8);

        f32x4 s[13];
#pragma unroll
        for (int rt = 0; rt < 13; ++rt) {
            f32x4 a = {0.f,0.f,0.f,0.f};
#pragma unroll
            for (int kk = 0; kk < 4; ++kk) {
                bf16x8v kf = *(const bf16x8v*)(kb + qkbase + (size_t)(rt*16 + fr)*128 + kk*32 + fq*8);
                a = MFMA16(qa[kk], kf, a);
            }
            s[rt] = a;
        }
        // add positional term, mask padded columns
#pragma unroll
        for (int rt = 0; rt < 13; ++rt) {
            int r = rt*16 + fr;
#pragma unroll
            for (int g = 0; g < 4; ++g) {
                int c = qc*16 + fq*4 + g;
                float v = s[rt][g];
                if (c < 200) v += tof(pb[((size_t)c*640 + blk)*208 + r]);
                if (r >= 200) v = -1e30f;
                s[rt][g] = v;
            }
        }
        // softmax per row (row lives in 16 lanes sharing fq, spread over 13 tiles)
        float mx[4] = {-3e38f,-3e38f,-3e38f,-3e38f};
#pragma unroll
        for (int rt = 0; rt < 13; ++rt)
#pragma unroll
            for (int g = 0; g < 4; ++g) mx[g] = fmaxf(mx[g], s[rt][g]);
#pragma unroll
        for (int m = 1; m < 16; m <<= 1)
#pragma unroll
            for (int g = 0; g < 4; ++g) mx[g] = fmaxf(mx[g], __shfl_xor(mx[g], m));
        float sm[4] = {0.f,0.f,0.f,0.f};
#pragma unroll
        for (int rt = 0; rt < 13; ++rt)
#pragma unroll
            for (int g = 0; g < 4; ++g) {
                float pv = __expf(s[rt][g] - mx[g]);
                s[rt][g] = pv; sm[g] += pv;
            }
#pragma unroll
        for (int m = 1; m < 16; m <<= 1)
#pragma unroll
            for (int g = 0; g < 4; ++g) sm[g] += __shfl_xor(sm[g], m);
        float inv[4];
#pragma unroll
        for (int g = 0; g < 4; ++g) inv[g] = 1.f / sm[g];
        // write P to LDS (bf16) in A-fragment layout
#pragma unroll
        for (int rt = 0; rt < 13; ++rt)
#pragma unroll
            for (int g = 0; g < 4; ++g)
                P[w][fq*4 + g][rt*16 + fr] = tob(s[rt][g] * inv[g]);
#pragma unroll
        for (int g = 0; g < 4; ++g) P[w][fq*4 + g][208 + fr] = tob(0.f);
        asm volatile("s_waitcnt lgkmcnt(0)" ::: "memory");
        __builtin_amdgcn_sched_barrier(0);

        // PV
        bf16x8v pa[7];
#pragma unroll
        for (int kt = 0; kt < 7; ++kt)
            pa[kt] = *(const bf16x8v*)(&P[w][fr][kt*32 + fq*8]);
#pragma unroll
        for (int nt = 0; nt < 8; ++nt) {
            f32x4 o = {0.f,0.f,0.f,0.f};
#pragma unroll
            for (int kt = 0; kt < 7; ++kt) {
                bf16x8v vf = *(const bf16x8v*)(vt + vbase + (size_t)(nt*16 + fr)*224 + kt*32 + fq*8);
                o = MFMA16(pa[kt], vf, o);
            }
            int d = nt*16 + fr;
#pragma unroll
            for (int g = 0; g < 4; ++g) {
                int c = qc*16 + fq*4 + g;
                if (c < 200)
                    ob[((size_t)(blk >> 3)*200 + c)*1024 + (blk & 7)*128 + d] = tob(o[g]);
            }
        }
    }
}

// ---------------- GLU in place over h[16000][4096]: h[:, :2048] = a*sigmoid(gate)
__global__ __launch_bounds__(256)
void glu_k(bf16* __restrict__ h)
{
    size_t idx = (size_t)blockIdx.x*256 + threadIdx.x;
    size_t row = idx >> 8; int c0 = (int)(idx & 255) * 8;
    bf16* pa = h + row*4096 + c0;
    const bf16* pg = h + row*4096 + 2048 + c0;
    union { uint4 u; bf16 hh[8]; } a, g, o;
    a.u = *(const uint4*)pa; g.u = *(const uint4*)pg;
#pragma unroll
    for (int j = 0; j < 8; ++j) {
        float av = tof(a.hh[j]), gv = tof(g.hh[j]);
        o.hh[j] = tob(av * (1.f / (1.f + __expf(-gv))));
    }
    *(uint4*)pa = o.u;
}

// ---------------- depthwise conv K=15 + BN + SiLU; in stride 4096 (glu half) ----
__global__ __launch_bounds__(256)
void dwconv(const bf16* __restrict__ h, const float* __restrict__ dw,
            const float* __restrict__ bng, const float* __restrict__ bnb,
            const float* __restrict__ bnm, const float* __restrict__ bnv,
            bf16* __restrict__ out)  // out = h + 2048 (same 4096 stride)
{
    int ch = blockIdx.x*256 + threadIdx.x;
    int b  = blockIdx.z;
    int n0 = blockIdx.y * 125;
    float wgt[15];
#pragma unroll
    for (int i = 0; i < 15; ++i) wgt[i] = dw[ch*15 + i];
    float sc = bng[ch] * rsqrtf(bnv[ch] + 1e-5f);
    float sh = bnb[ch] - bnm[ch]*sc;
    const size_t rowbase = (size_t)b*2000;
    float win[15];
#pragma unroll
    for (int i = 0; i < 15; ++i) {
        int nn = n0 - 7 + i;
        win[i] = (nn >= 0 && nn < 2000) ? tof(h[(rowbase + nn)*4096 + ch]) : 0.f;
    }
    for (int j = 0; j < 125; ++j) {
        int n = n0 + j;
        float a = 0.f;
#pragma unroll
        for (int i = 0; i < 15; ++i) a += win[i]*wgt[i];
        float y = a*sc + sh;
        y = y * (1.f / (1.f + __expf(-y)));
        out[(rowbase + n)*4096 + ch] = tob(y);
#pragma unroll
        for (int i = 0; i < 14; ++i) win[i] = win[i+1];
        int nn = n + 8;
        win[14] = (nn < 2000) ? tof(h[(rowbase + nn)*4096 + ch]) : 0.f;
    }
}

extern "C" void kernel_launch(void* const* d_in, const int* in_sizes, int n_in,
                              void* d_out, int out_size, void* d_ws, size_t ws_size,
                              hipStream_t stream)
{
    (void)in_sizes; (void)n_in; (void)out_size; (void)ws_size;
    const float* x      = (const float*)d_in[0];
    const int*   dists  = (const int*)d_in[1];
    const float* ff1_ng = (const float*)d_in[2];
    const float* ff1_nb = (const float*)d_in[3];
    const float* ff1_w1 = (const float*)d_in[4];
    const float* ff1_b1 = (const float*)d_in[5];
    const float* ff1_w2 = (const float*)d_in[6];
    const float* ff1_b2 = (const float*)d_in[7];
    const float* attn_ng= (const float*)d_in[8];
    const float* attn_nb= (const float*)d_in[9];
    const float* wq     = (const float*)d_in[10];
    const float* wkv    = (const float*)d_in[11];
    const float* pos_emb= (const float*)d_in[12];
    const float* wo     = (const float*)d_in[13];
    const float* bo     = (const float*)d_in[14];
    const float* conv_ng= (const float*)d_in[15];
    const float* conv_nb= (const float*)d_in[16];
    const float* pw1_w  = (const float*)d_in[17];
    const float* pw1_b  = (const float*)d_in[18];
    const float* dw_w   = (const float*)d_in[19];
    const float* bn_g   = (const float*)d_in[20];
    const float* bn_b   = (const float*)d_in[21];
    const float* bn_m   = (const float*)d_in[22];
    const float* bn_v   = (const float*)d_in[23];
    const float* pw2_w  = (const float*)d_in[24];
    const float* pw2_b  = (const float*)d_in[25];
    const float* ff2_ng = (const float*)d_in[26];
    const float* ff2_nb = (const float*)d_in[27];
    const float* ff2_w1 = (const float*)d_in[28];
    const float* ff2_b1 = (const float*)d_in[29];
    const float* ff2_w2 = (const float*)d_in[30];
    const float* ff2_b2 = (const float*)d_in[31];
    const float* post_g = (const float*)d_in[32];
    const float* post_b = (const float*)d_in[33];

    // residual stream lives in d_out (f32 [16000][1024]); fully written by FF1's
    // epilogue before any read, final LN runs in-place on it.
    float* xres = (float*)d_out;

    char* p = (char*)d_ws;
    bf16*  xn    = (bf16*)p;   p += 32768000;     // [16000][1024] bf16 (LN out / attn O)
    bf16* ff1w1T = (bf16*)p;   p += 8388608;
    bf16* ff1w2T = (bf16*)p;   p += 8388608;
    bf16* qkvT   = (bf16*)p;   p += 6291456;
    bf16* woT    = (bf16*)p;   p += 2097152;
    bf16* pw1T   = (bf16*)p;   p += 8388608;
    bf16* pw2T   = (bf16*)p;   p += 4194304;
    bf16* ff2w1T = (bf16*)p;   p += 8388608;
    bf16* ff2w2T = (bf16*)p;   p += 8388608;
    char* trans  = p;                              // 158,105,600 B region (total ws 234 MiB)
    bf16* qbuf = (bf16*)trans;                     // [640][208][128]
    bf16* kbuf = qbuf + (size_t)640*208*128;       // [640][208][128]
    bf16* vT   = kbuf + (size_t)640*208*128;       // [640][128][224]
    bf16* posb = vT   + (size_t)640*128*224;       // [200][640][208]
    bf16* hbuf = (bf16*)trans;                     // [16000][4096] (aliases attn bufs)

    // ---- weight prep (transpose to [N][K] bf16) ----
    transpose_cast<<<dim3(128, 32), 256, 0, stream>>>(ff1_w1, ff1w1T, 1024, 4096);
    transpose_cast<<<dim3(32, 128), 256, 0, stream>>>(ff1_w2, ff1w2T, 4096, 1024);
    transpose_cast<<<dim3(32, 32),  256, 0, stream>>>(wq, qkvT, 1024, 1024);
    transpose_cast<<<dim3(64, 32),  256, 0, stream>>>(wkv, qkvT + (size_t)1024*1024, 1024, 2048);
    transpose_cast<<<dim3(32, 32),  256, 0, stream>>>(wo, woT, 1024, 1024);
    transpose_cast<<<dim3(128, 32), 256, 0, stream>>>(pw1_w, pw1T, 1024, 4096);
    transpose_cast<<<dim3(32, 64),  256, 0, stream>>>(pw2_w, pw2T, 2048, 1024);
    transpose_cast<<<dim3(128, 32), 256, 0, stream>>>(ff2_w1, ff2w1T, 1024, 4096);
    transpose_cast<<<dim3(32, 128), 256, 0, stream>>>(ff2_w2, ff2w2T, 4096, 1024);

    // ---- FF1: xres = x + 0.5*FF(x) ----
    ln_k<false><<<16000, 256, 0, stream>>>(x, ff1_ng, ff1_nb, xn);
    gemm_bt<0><<<dim3(32,125), 256, 0, stream>>>(xn, ff1w1T, 16000,4096,1024,1024,
                                                 ff1_b1, nullptr, 0.f, hbuf, nullptr, nullptr);
    gemm_bt<2><<<dim3(8,125), 256, 0, stream>>>(hbuf, ff1w2T, 16000,1024,4096,4096,
                                                ff1_b2, x, 0.5f, xres, nullptr, nullptr);

    // ---- attention ----
    ln_k<false><<<16000, 256, 0, stream>>>(xres, attn_ng, attn_nb, xn);
    zero_k<<<2048, 256, 0, stream>>>((uint4*)qbuf, (size_t)104857600/16); // q,k,vT pad zero
    gemm_bt<3><<<dim3(24,125), 256, 0, stream>>>(xn, qkvT, 16000,3072,1024,1024,
                                                 nullptr, nullptr, 0.f, qbuf, kbuf, vT);
    pos_kernel<<<dim3(10,200), 64, 0, stream>>>(qbuf, pos_emb, dists, posb);
    attn_core<<<640, 256, 0, stream>>>(qbuf, kbuf, vT, posb, xn);   // xn = O (bf16)
    gemm_bt<2><<<dim3(8,125), 256, 0, stream>>>(xn, woT, 16000,1024,1024,1024,
                                                bo, xres, 1.f, xres, nullptr, nullptr);

    // ---- conv module ----
    ln_k<false><<<16000, 256, 0, stream>>>(xres, conv_ng, conv_nb, xn);
    gemm_bt<1><<<dim3(32,125), 256, 0, stream>>>(xn, pw1T, 16000,4096,1024,1024,
                                                 pw1_b, nullptr, 0.f, hbuf, nullptr, nullptr);
    glu_k<<<16000, 256, 0, stream>>>(hbuf);
    dwconv<<<dim3(8,16,8), 256, 0, stream>>>(hbuf, dw_w, bn_g, bn_b, bn_m, bn_v, hbuf + 2048);
    gemm_bt<2><<<dim3(8,125), 256, 0, stream>>>(hbuf + 2048, pw2T, 16000,1024,2048,4096,
                                                pw2_b, xres, 1.f, xres, nullptr, nullptr);

    // ---- FF2 ----
    ln_k<false><<<16000, 256, 0, stream>>>(xres, ff2_ng, ff2_nb, xn);
    gemm_bt<0><<<dim3(32,125), 256, 0, stream>>>(xn, ff2w1T, 16000,4096,1024,1024,
                                                 ff2_b1, nullptr, 0.f, hbuf, nullptr, nullptr);
    gemm_bt<2><<<dim3(8,125), 256, 0, stream>>>(hbuf, ff2w2T, 16000,1024,4096,4096,
                                                ff2_b2, xres, 0.5f, xres, nullptr, nullptr);

    // ---- final LN in place on d_out ----
    ln_k<true><<<16000, 256, 0, stream>>>(xres, post_g, post_b, d_out);
}

// Round 3
// 1877.288 us; speedup vs baseline: 1.0702x; 1.0702x over previous
//
#include <hip/hip_runtime.h>
#include <hip/hip_bf16.h>
#include <stdint.h>

using bf16 = __hip_bfloat16;
typedef __bf16 bf16x8v __attribute__((ext_vector_type(8)));
typedef float f32x4 __attribute__((ext_vector_type(4)));

#define MFMA16(a,b,c) __builtin_amdgcn_mfma_f32_16x16x32_bf16((a),(b),(c),0,0,0)

__device__ __forceinline__ float tof(bf16 h){ return __bfloat162float(h); }
__device__ __forceinline__ bf16 tob(float f){ return __float2bfloat16(f); }

__device__ __forceinline__ void gll16(const void* g, void* l) {
    __builtin_amdgcn_global_load_lds((const __attribute__((address_space(1))) void*)g,
                                     (__attribute__((address_space(3))) void*)l, 16, 0, 0);
}

// ---------------- pad-only zero for q/k (rows 200..207) and vT (cols 200..223) ----
__global__ __launch_bounds__(256)
void pad_zero(bf16* __restrict__ q, bf16* __restrict__ k, bf16* __restrict__ v)
{
    int blk = blockIdx.x, t = threadIdx.x;
    uint2 z = make_uint2(0u, 0u);
    size_t qk = (size_t)blk * 208 * 128;
    int r = 200 + (t >> 5), c = (t & 31) * 4;
    *(uint2*)(q + qk + r*128 + c) = z;
    *(uint2*)(k + qk + r*128 + c) = z;
    size_t vb = (size_t)blk * 128 * 224;
    int d = t >> 1, c0 = 200 + (t & 1) * 12;
    *(uint2*)(v + vb + d*224 + c0)     = z;
    *(uint2*)(v + vb + d*224 + c0 + 4) = z;
    *(uint2*)(v + vb + d*224 + c0 + 8) = z;
}

// ---------------- cast pos_emb f32 -> bf16 (1025*128 = 16400 groups of 8) ----
__global__ __launch_bounds__(256)
void cast_pe(const float* __restrict__ in, bf16* __restrict__ out, int n8)
{
    int i = blockIdx.x * 256 + threadIdx.x;
    if (i >= n8) return;
    f32x4 a = ((const f32x4*)in)[2*i], b = ((const f32x4*)in)[2*i + 1];
    union { uint4 u; bf16 h[8]; } o;
#pragma unroll
    for (int j = 0; j < 4; ++j) { o.h[j] = tob(a[j]); o.h[4+j] = tob(b[j]); }
    ((uint4*)out)[i] = o.u;
}

// ---------------- transpose + cast: out[c][r] = (bf16)in[r][c] ----------------
__global__ __launch_bounds__(256)
void transpose_cast(const float* __restrict__ in, bf16* __restrict__ out, int R, int C)
{
    __shared__ float t[32][33];
    int bx = blockIdx.x * 32, by = blockIdx.y * 32;
    int tx = threadIdx.x & 31, ty = threadIdx.x >> 5;
#pragma unroll
    for (int i = 0; i < 4; ++i)
        t[ty + i*8][tx] = in[(size_t)(by + ty + i*8) * C + bx + tx];
    __syncthreads();
#pragma unroll
    for (int i = 0; i < 4; ++i)
        out[(size_t)(bx + ty + i*8) * R + by + tx] = tob(t[tx][ty + i*8]);
}

// ---------------- LayerNorm over 1024, one block per row ----------------
template<bool OUT32>
__global__ __launch_bounds__(256)
void ln_k(const float* __restrict__ x, const float* __restrict__ g,
          const float* __restrict__ b, void* __restrict__ out)
{
    int row = blockIdx.x, tid = threadIdx.x;
    const float4 v = ((const float4*)(x + (size_t)row*1024))[tid];
    float s = v.x + v.y + v.z + v.w;
    float q = v.x*v.x + v.y*v.y + v.z*v.z + v.w*v.w;
#pragma unroll
    for (int m = 1; m < 64; m <<= 1) { s += __shfl_xor(s, m); q += __shfl_xor(q, m); }
    __shared__ float red[8];
    if ((tid & 63) == 0) { red[tid>>6] = s; red[4 + (tid>>6)] = q; }
    __syncthreads();
    float ts = red[0]+red[1]+red[2]+red[3];
    float tq = red[4]+red[5]+red[6]+red[7];
    float mean = ts * (1.f/1024.f);
    float var  = tq * (1.f/1024.f) - mean*mean;
    float rs = rsqrtf(var + 1e-5f);
    const float4 gv = ((const float4*)g)[tid];
    const float4 bv = ((const float4*)b)[tid];
    float o0 = (v.x-mean)*rs*gv.x + bv.x;
    float o1 = (v.y-mean)*rs*gv.y + bv.y;
    float o2 = (v.z-mean)*rs*gv.z + bv.z;
    float o3 = (v.w-mean)*rs*gv.w + bv.w;
    if (OUT32) {
        ((float4*)out)[(size_t)row*256 + tid] = make_float4(o0,o1,o2,o3);
    } else {
        bf16 tmp[4] = { tob(o0), tob(o1), tob(o2), tob(o3) };
        ((uint2*)out)[(size_t)row*256 + tid] = *(const uint2*)tmp;
    }
}

// ---------------- GEMM: C[M,N] = A[M,K](lda) @ BT[N,K]^T, bf16 in, fp32 acc ----
// EP 0: bias+silu -> bf16 (ld=N)   EP 1: bias -> bf16 (ld=N)
// EP 2: resid + alpha*(acc+bias) -> f32 (ld=N)
// EP 3: qkv scatter (o0=q blocked *SCALE, o1=k blocked, o2=v transposed)
template<int EP>
__global__ __launch_bounds__(256, 2)
void gemm_bt(const bf16* __restrict__ A, const bf16* __restrict__ BT,
             int M, int N, int K, int lda,
             const float* __restrict__ bias, const float* resid, float alpha,
             void* o0, void* o1, void* o2)
{
    (void)M;
    __shared__ bf16 sA[2][4096];
    __shared__ bf16 sB[2][4096];
    const int tid = threadIdx.x;
    const int lane = tid & 63, wid = tid >> 6;
    const int wm = wid >> 1, wn = wid & 1;
    const int bn0 = blockIdx.x * 128, bm0 = blockIdx.y * 128;
    const int fr = lane & 15, fq = lane >> 4;
    const int nk = K >> 5;

    f32x4 acc[4][4];
    const f32x4 vzero = {0.f, 0.f, 0.f, 0.f};
#pragma unroll
    for (int i = 0; i < 4; ++i)
#pragma unroll
        for (int j = 0; j < 4; ++j) acc[i][j] = vzero;

    const bf16* Abase = A + (size_t)bm0 * lda;
    const bf16* Bbase = BT + (size_t)bn0 * K;

    auto stage = [&](int kb, int buf) {
#pragma unroll
        for (int rd = 0; rd < 2; ++rd) {
            int s = rd*256 + tid;
            int r = s >> 2, ko = (s & 3) * 8;
            gll16(Abase + (size_t)r*lda + kb*32 + ko, &sA[buf][s*8]);
            gll16(Bbase + (size_t)r*K   + kb*32 + ko, &sB[buf][s*8]);
        }
    };

    stage(0, 0);
    for (int kb = 0; kb < nk; ++kb) {
        __syncthreads();
        if (kb + 1 < nk) stage(kb+1, (kb+1) & 1);
        const bf16* sa = sA[kb & 1];
        const bf16* sb = sB[kb & 1];
        bf16x8v af[4], bfv[4];
#pragma unroll
        for (int mi = 0; mi < 4; ++mi)
            af[mi] = *(const bf16x8v*)(sa + (wm*64 + mi*16 + fr)*32 + fq*8);
#pragma unroll
        for (int ni = 0; ni < 4; ++ni)
            bfv[ni] = *(const bf16x8v*)(sb + (wn*64 + ni*16 + fr)*32 + fq*8);
#pragma unroll
        for (int mi = 0; mi < 4; ++mi)
#pragma unroll
            for (int ni = 0; ni < 4; ++ni)
                acc[mi][ni] = MFMA16(af[mi], bfv[ni], acc[mi][ni]);
    }

#pragma unroll
    for (int mi = 0; mi < 4; ++mi)
#pragma unroll
    for (int ni = 0; ni < 4; ++ni)
#pragma unroll
    for (int r = 0; r < 4; ++r) {
        int row = bm0 + wm*64 + mi*16 + fq*4 + r;
        int col = bn0 + wn*64 + ni*16 + fr;
        float v = acc[mi][ni][r];
        if (EP == 0) {
            v += bias[col];
            v = v * (1.f / (1.f + __expf(-v)));
            ((bf16*)o0)[(size_t)row * N + col] = tob(v);
        } else if (EP == 1) {
            v += bias[col];
            ((bf16*)o0)[(size_t)row * N + col] = tob(v);
        } else if (EP == 2) {
            float o = resid[(size_t)row * N + col] + alpha * (v + bias[col]);
            ((float*)o0)[(size_t)row * N + col] = o;
        } else {
            int sec = col >> 10, hh = (col >> 7) & 7, d = col & 127;
            int blk = (row / 200) * 8 + hh, c = row % 200;
            if (sec == 0)      ((bf16*)o0)[((size_t)blk*208 + c)*128 + d] = tob(v * 0.08838834764831845f);
            else if (sec == 1) ((bf16*)o1)[((size_t)blk*208 + c)*128 + d] = tob(v);
            else               ((bf16*)o2)[((size_t)blk*128 + d)*224 + c] = tob(v);
        }
    }
}

// ---------------- Shaw positional scores: pos[c][bmh][r] = q[bmh,c,:]·peb[dists[c,r],:]
// grid (10, 200): one wave computes 64 bmh rows x 208 r for a fixed c.
__global__ __launch_bounds__(64)
void pos_kernel(const bf16* __restrict__ qb, const bf16* __restrict__ peb,
                const int* __restrict__ dists, bf16* __restrict__ pbuf)
{
    const int c = blockIdx.y, mt = blockIdx.x;
    const int lane = threadIdx.x;
    const int fr = lane & 15, fq = lane >> 4;
    bf16x8v qa[4][4];
#pragma unroll
    for (int sub = 0; sub < 4; ++sub)
#pragma unroll
        for (int kk = 0; kk < 4; ++kk)
            qa[sub][kk] = *(const bf16x8v*)(qb + ((size_t)(mt*64 + sub*16 + fr)*208 + c)*128 + kk*32 + fq*8);

    for (int rt = 0; rt < 13; ++rt) {
        int r = rt*16 + fr;
        int pidx = (r < 200) ? dists[c*200 + r] : 0;
        bf16x8v bv[4];
#pragma unroll
        for (int kk = 0; kk < 4; ++kk)
            bv[kk] = *(const bf16x8v*)(peb + (size_t)pidx*128 + kk*32 + fq*8);
#pragma unroll
        for (int sub = 0; sub < 4; ++sub) {
            f32x4 a = {0.f,0.f,0.f,0.f};
#pragma unroll
            for (int kk = 0; kk < 4; ++kk) a = MFMA16(qa[sub][kk], bv[kk], a);
            int bmh = mt*64 + sub*16 + fq*4;
#pragma unroll
            for (int g = 0; g < 4; ++g)
                pbuf[((size_t)c*640 + bmh + g)*208 + r] = tob(a[g]);
        }
    }
}

// ---------------- attention core: one WAVE per (blk, qc); transposed scores ----
// S^T = mfma(K, Q): D[row=r (fq*4+g)][col=c (fr)]. Softmax over r = in-lane 13x4
// + shfl_xor(16,32). pos add = uint2 load (4 consecutive r). P re-layout via LDS.
__global__ __launch_bounds__(64, 4)
void attn_core(const bf16* __restrict__ qb, const bf16* __restrict__ kb,
               const bf16* __restrict__ vt, const bf16* __restrict__ pb,
               bf16* __restrict__ ob)
{
    __shared__ bf16 P[16][232];   // [c][r], padded stride vs 224 to spread banks
    const int blk = blockIdx.x, qc = blockIdx.y;
    const int lane = threadIdx.x;
    const int fr = lane & 15, fq = lane >> 4;
    const size_t qkbase = (size_t)blk * 208 * 128;
    const size_t vbase  = (size_t)blk * 128 * 224;
    const int c = qc*16 + fr;            // this lane's score column (q row)

    bf16x8v qa[4];
#pragma unroll
    for (int kk = 0; kk < 4; ++kk)
        qa[kk] = *(const bf16x8v*)(qb + qkbase + (size_t)(qc*16 + fr)*128 + kk*32 + fq*8);

    f32x4 s[13];
#pragma unroll
    for (int rt = 0; rt < 13; ++rt) {
        f32x4 a = {0.f,0.f,0.f,0.f};
#pragma unroll
        for (int kk = 0; kk < 4; ++kk) {
            bf16x8v kf = *(const bf16x8v*)(kb + qkbase + (size_t)(rt*16 + fr)*128 + kk*32 + fq*8);
            a = MFMA16(kf, qa[kk], a);
        }
        s[rt] = a;
    }
    // add positional term (vector load: 4 consecutive r), mask padded key rows
#pragma unroll
    for (int rt = 0; rt < 13; ++rt) {
        if (c < 200) {
            union { uint2 u; bf16 h[4]; } pv;
            pv.u = *(const uint2*)(pb + ((size_t)c*640 + blk)*208 + rt*16 + fq*4);
#pragma unroll
            for (int g = 0; g < 4; ++g) s[rt][g] += tof(pv.h[g]);
        }
        if (rt == 12 && fq >= 2) {
#pragma unroll
            for (int g = 0; g < 4; ++g)
                if (fq*4 + g >= 8) s[rt][g] = -1e30f;
        }
    }
    // softmax over r: in-lane 13x4, then across the 4 fq groups
    float mx = -3e38f;
#pragma unroll
    for (int rt = 0; rt < 13; ++rt)
#pragma unroll
        for (int g = 0; g < 4; ++g) mx = fmaxf(mx, s[rt][g]);
    mx = fmaxf(mx, __shfl_xor(mx, 16));
    mx = fmaxf(mx, __shfl_xor(mx, 32));
    float sm = 0.f;
#pragma unroll
    for (int rt = 0; rt < 13; ++rt)
#pragma unroll
        for (int g = 0; g < 4; ++g) { float pv = __expf(s[rt][g] - mx); s[rt][g] = pv; sm += pv; }
    sm += __shfl_xor(sm, 16);
    sm += __shfl_xor(sm, 32);
    float inv = 1.f / sm;
    // write P^T regs -> P[c][r] LDS (uint2 = 4 bf16 along r)
#pragma unroll
    for (int rt = 0; rt < 13; ++rt) {
        union { uint2 u; bf16 h[4]; } pw;
#pragma unroll
        for (int g = 0; g < 4; ++g) pw.h[g] = tob(s[rt][g] * inv);
        *(uint2*)&P[fr][rt*16 + fq*4] = pw.u;
    }
    *(uint2*)&P[fr][208 + fq*4] = make_uint2(0u, 0u);   // zero r pad 208..223

    // PV: O[c][d] = mfma(A = P rows c, B = V^T rows d)
    bf16x8v pa[7];
#pragma unroll
    for (int kt = 0; kt < 7; ++kt)
        pa[kt] = *(const bf16x8v*)(&P[fr][kt*32 + fq*8]);
#pragma unroll
    for (int nt = 0; nt < 8; ++nt) {
        f32x4 o = {0.f,0.f,0.f,0.f};
#pragma unroll
        for (int kt = 0; kt < 7; ++kt) {
            bf16x8v vf = *(const bf16x8v*)(vt + vbase + (size_t)(nt*16 + fr)*224 + kt*32 + fq*8);
            o = MFMA16(pa[kt], vf, o);
        }
        int d = nt*16 + fr;
#pragma unroll
        for (int g = 0; g < 4; ++g) {
            int cc = qc*16 + fq*4 + g;
            if (cc < 200)
                ob[((size_t)(blk >> 3)*200 + cc)*1024 + (blk & 7)*128 + d] = tob(o[g]);
        }
    }
}

// ---------------- GLU in place over h[16000][4096]: h[:, :2048] = a*sigmoid(gate)
__global__ __launch_bounds__(256)
void glu_k(bf16* __restrict__ h)
{
    size_t idx = (size_t)blockIdx.x*256 + threadIdx.x;
    size_t row = idx >> 8; int c0 = (int)(idx & 255) * 8;
    bf16* pa = h + row*4096 + c0;
    const bf16* pg = h + row*4096 + 2048 + c0;
    union { uint4 u; bf16 hh[8]; } a, g, o;
    a.u = *(const uint4*)pa; g.u = *(const uint4*)pg;
#pragma unroll
    for (int j = 0; j < 8; ++j) {
        float av = tof(a.hh[j]), gv = tof(g.hh[j]);
        o.hh[j] = tob(av * (1.f / (1.f + __expf(-gv))));
    }
    *(uint4*)pa = o.u;
}

// ---------------- depthwise conv K=15 + BN + SiLU; in stride 4096 (glu half) ----
__global__ __launch_bounds__(256)
void dwconv(const bf16* __restrict__ h, const float* __restrict__ dw,
            const float* __restrict__ bng, const float* __restrict__ bnb,
            const float* __restrict__ bnm, const float* __restrict__ bnv,
            bf16* __restrict__ out)  // out = h + 2048 (same 4096 stride)
{
    int ch = blockIdx.x*256 + threadIdx.x;
    int b  = blockIdx.z;
    int n0 = blockIdx.y * 125;
    float wgt[15];
#pragma unroll
    for (int i = 0; i < 15; ++i) wgt[i] = dw[ch*15 + i];
    float sc = bng[ch] * rsqrtf(bnv[ch] + 1e-5f);
    float sh = bnb[ch] - bnm[ch]*sc;
    const size_t rowbase = (size_t)b*2000;
    float win[15];
#pragma unroll
    for (int i = 0; i < 15; ++i) {
        int nn = n0 - 7 + i;
        win[i] = (nn >= 0 && nn < 2000) ? tof(h[(rowbase + nn)*4096 + ch]) : 0.f;
    }
    for (int j = 0; j < 125; ++j) {
        int n = n0 + j;
        float a = 0.f;
#pragma unroll
        for (int i = 0; i < 15; ++i) a += win[i]*wgt[i];
        float y = a*sc + sh;
        y = y * (1.f / (1.f + __expf(-y)));
        out[(rowbase + n)*4096 + ch] = tob(y);
#pragma unroll
        for (int i = 0; i < 14; ++i) win[i] = win[i+1];
        int nn = n + 8;
        win[14] = (nn < 2000) ? tof(h[(rowbase + nn)*4096 + ch]) : 0.f;
    }
}

extern "C" void kernel_launch(void* const* d_in, const int* in_sizes, int n_in,
                              void* d_out, int out_size, void* d_ws, size_t ws_size,
                              hipStream_t stream)
{
    (void)in_sizes; (void)n_in; (void)out_size; (void)ws_size;
    const float* x      = (const float*)d_in[0];
    const int*   dists  = (const int*)d_in[1];
    const float* ff1_ng = (const float*)d_in[2];
    const float* ff1_nb = (const float*)d_in[3];
    const float* ff1_w1 = (const float*)d_in[4];
    const float* ff1_b1 = (const float*)d_in[5];
    const float* ff1_w2 = (const float*)d_in[6];
    const float* ff1_b2 = (const float*)d_in[7];
    const float* attn_ng= (const float*)d_in[8];
    const float* attn_nb= (const float*)d_in[9];
    const float* wq     = (const float*)d_in[10];
    const float* wkv    = (const float*)d_in[11];
    const float* pos_emb= (const float*)d_in[12];
    const float* wo     = (const float*)d_in[13];
    const float* bo     = (const float*)d_in[14];
    const float* conv_ng= (const float*)d_in[15];
    const float* conv_nb= (const float*)d_in[16];
    const float* pw1_w  = (const float*)d_in[17];
    const float* pw1_b  = (const float*)d_in[18];
    const float* dw_w   = (const float*)d_in[19];
    const float* bn_g   = (const float*)d_in[20];
    const float* bn_b   = (const float*)d_in[21];
    const float* bn_m   = (const float*)d_in[22];
    const float* bn_v   = (const float*)d_in[23];
    const float* pw2_w  = (const float*)d_in[24];
    const float* pw2_b  = (const float*)d_in[25];
    const float* ff2_ng = (const float*)d_in[26];
    const float* ff2_nb = (const float*)d_in[27];
    const float* ff2_w1 = (const float*)d_in[28];
    const float* ff2_b1 = (const float*)d_in[29];
    const float* ff2_w2 = (const float*)d_in[30];
    const float* ff2_b2 = (const float*)d_in[31];
    const float* post_g = (const float*)d_in[32];
    const float* post_b = (const float*)d_in[33];

    // residual stream lives in d_out (f32 [16000][1024]); fully written by FF1's
    // epilogue before any read, final LN runs in-place on it.
    float* xres = (float*)d_out;

    char* p = (char*)d_ws;
    bf16*  xn    = (bf16*)p;   p += 32768000;     // [16000][1024] bf16 (LN out / attn O)
    bf16* ff1w1T = (bf16*)p;   p += 8388608;
    bf16* ff1w2T = (bf16*)p;   p += 8388608;
    bf16* qkvT   = (bf16*)p;   p += 6291456;
    bf16* woT    = (bf16*)p;   p += 2097152;
    bf16* pw1T   = (bf16*)p;   p += 8388608;
    bf16* pw2T   = (bf16*)p;   p += 4194304;
    bf16* ff2w1T = (bf16*)p;   p += 8388608;
    bf16* ff2w2T = (bf16*)p;   p += 8388608;
    bf16* peb    = (bf16*)p;   p += 262400;       // pos_emb bf16 [1025][128]
    char* trans  = p;                              // 158,105,600 B region
    bf16* qbuf = (bf16*)trans;                     // [640][208][128]
    bf16* kbuf = qbuf + (size_t)640*208*128;       // [640][208][128]
    bf16* vT   = kbuf + (size_t)640*208*128;       // [640][128][224]
    bf16* posb = vT   + (size_t)640*128*224;       // [200][640][208]
    bf16* hbuf = (bf16*)trans;                     // [16000][4096] (aliases attn bufs)

    // ---- weight prep (transpose to [N][K] bf16) ----
    transpose_cast<<<dim3(128, 32), 256, 0, stream>>>(ff1_w1, ff1w1T, 1024, 4096);
    transpose_cast<<<dim3(32, 128), 256, 0, stream>>>(ff1_w2, ff1w2T, 4096, 1024);
    transpose_cast<<<dim3(32, 32),  256, 0, stream>>>(wq, qkvT, 1024, 1024);
    transpose_cast<<<dim3(64, 32),  256, 0, stream>>>(wkv, qkvT + (size_t)1024*1024, 1024, 2048);
    transpose_cast<<<dim3(32, 32),  256, 0, stream>>>(wo, woT, 1024, 1024);
    transpose_cast<<<dim3(128, 32), 256, 0, stream>>>(pw1_w, pw1T, 1024, 4096);
    transpose_cast<<<dim3(32, 64),  256, 0, stream>>>(pw2_w, pw2T, 2048, 1024);
    transpose_cast<<<dim3(128, 32), 256, 0, stream>>>(ff2_w1, ff2w1T, 1024, 4096);
    transpose_cast<<<dim3(32, 128), 256, 0, stream>>>(ff2_w2, ff2w2T, 4096, 1024);
    cast_pe<<<65, 256, 0, stream>>>(pos_emb, peb, 16400);

    // ---- FF1: xres = x + 0.5*FF(x) ----
    ln_k<false><<<16000, 256, 0, stream>>>(x, ff1_ng, ff1_nb, xn);
    gemm_bt<0><<<dim3(32,125), 256, 0, stream>>>(xn, ff1w1T, 16000,4096,1024,1024,
                                                 ff1_b1, nullptr, 0.f, hbuf, nullptr, nullptr);
    gemm_bt<2><<<dim3(8,125), 256, 0, stream>>>(hbuf, ff1w2T, 16000,1024,4096,4096,
                                                ff1_b2, x, 0.5f, xres, nullptr, nullptr);

    // ---- attention ----
    ln_k<false><<<16000, 256, 0, stream>>>(xres, attn_ng, attn_nb, xn);
    pad_zero<<<640, 256, 0, stream>>>(qbuf, kbuf, vT);
    gemm_bt<3><<<dim3(24,125), 256, 0, stream>>>(xn, qkvT, 16000,3072,1024,1024,
                                                 nullptr, nullptr, 0.f, qbuf, kbuf, vT);
    pos_kernel<<<dim3(10,200), 64, 0, stream>>>(qbuf, peb, dists, posb);
    attn_core<<<dim3(640,13), 64, 0, stream>>>(qbuf, kbuf, vT, posb, xn);   // xn = O
    gemm_bt<2><<<dim3(8,125), 256, 0, stream>>>(xn, woT, 16000,1024,1024,1024,
                                                bo, xres, 1.f, xres, nullptr, nullptr);

    // ---- conv module ----
    ln_k<false><<<16000, 256, 0, stream>>>(xres, conv_ng, conv_nb, xn);
    gemm_bt<1><<<dim3(32,125), 256, 0, stream>>>(xn, pw1T, 16000,4096,1024,1024,
                                                 pw1_b, nullptr, 0.f, hbuf, nullptr, nullptr);
    glu_k<<<16000, 256, 0, stream>>>(hbuf);
    dwconv<<<dim3(8,16,8), 256, 0, stream>>>(hbuf, dw_w, bn_g, bn_b, bn_m, bn_v, hbuf + 2048);
    gemm_bt<2><<<dim3(8,125), 256, 0, stream>>>(hbuf + 2048, pw2T, 16000,1024,2048,4096,
                                                pw2_b, xres, 1.f, xres, nullptr, nullptr);

    // ---- FF2 ----
    ln_k<false><<<16000, 256, 0, stream>>>(xres, ff2_ng, ff2_nb, xn);
    gemm_bt<0><<<dim3(32,125), 256, 0, stream>>>(xn, ff2w1T, 16000,4096,1024,1024,
                                                 ff2_b1, nullptr, 0.f, hbuf, nullptr, nullptr);
    gemm_bt<2><<<dim3(8,125), 256, 0, stream>>>(hbuf, ff2w2T, 16000,1024,4096,4096,
                                                ff2_b2, xres, 0.5f, xres, nullptr, nullptr);

    // ---- final LN in place on d_out ----
    ln_k<true><<<16000, 256, 0, stream>>>(xres, post_g, post_b, d_out);
}